// Round 6
// baseline (205.028 us; speedup 1.0000x reference)
//
#include <hip/hip_runtime.h>
#include <hip/hip_bf16.h>
#include <math.h>
#include <stdint.h>

#define NB 4
#define NS 2048
#define ND 512
#define NH 8
#define DEP 64

typedef __attribute__((ext_vector_type(8))) short bf16x8;
typedef __attribute__((ext_vector_type(4))) short bf16x4;
typedef __attribute__((ext_vector_type(4))) float f32x4;

#define QSCALE 0.18033688011112042f  // DEPTH^-0.5 * log2(e): softmax in exp2

__device__ __forceinline__ short f2b(float f) {
  unsigned u = __float_as_uint(f);
  u += 0x7FFF + ((u >> 16) & 1);  // RNE
  return (short)(u >> 16);
}
__device__ __forceinline__ unsigned pk2(float a, float b) {
  union { __hip_bfloat162 h; unsigned u; } c;
  c.h = __float22bfloat162_rn(float2{a, b});
  return c.u;
}
// async 16B global->LDS DMA; LDS dest is wave-uniform base + lane*16
__device__ __forceinline__ void dma16(const void* g, void* l) {
  __builtin_amdgcn_global_load_lds(
      (const __attribute__((address_space(1))) void*)g,
      (__attribute__((address_space(3))) void*)l, 16, 0, 0);
}

// ---------------------------------------------------------------------------
__global__ __launch_bounds__(256) void cast_xy(const float* __restrict__ x,
                                               const float* __restrict__ y,
                                               short* __restrict__ xb,
                                               short* __restrict__ yb) {
  const float* src = blockIdx.y ? y : x;
  short* dst = blockIdx.y ? yb : xb;
  size_t i = ((size_t)blockIdx.x * 256 + threadIdx.x) * 4;
  float4 v = *(const float4*)(src + i);
  bf16x4 o;
  o[0] = f2b(v.x); o[1] = f2b(v.y); o[2] = f2b(v.z); o[3] = f2b(v.w);
  *(bf16x4*)(dst + i) = o;
}

// ---------------------------------------------------------------------------
// transpose + cast W[512][512] fp32 -> Wt[512][512] bf16 (Wt[n][k] = W[k][n])
// ---------------------------------------------------------------------------
__global__ __launch_bounds__(256) void trans_w(
    const float* __restrict__ W0, const float* __restrict__ W1,
    const float* __restrict__ W2, const float* __restrict__ W3,
    short* __restrict__ T0, short* __restrict__ T1, short* __restrict__ T2,
    short* __restrict__ T3) {
  const float* W = blockIdx.z == 0 ? W0 : blockIdx.z == 1 ? W1
                   : blockIdx.z == 2 ? W2 : W3;
  short* T = blockIdx.z == 0 ? T0 : blockIdx.z == 1 ? T1
             : blockIdx.z == 2 ? T2 : T3;
  __shared__ float tile[64][65];
  const int t = threadIdx.x;
  const int k0 = blockIdx.x * 64, n0 = blockIdx.y * 64;
#pragma unroll
  for (int i = 0; i < 4; ++i) {
    int r = (t >> 4) + i * 16;
    int c = (t & 15) * 4;
    float4 v = *(const float4*)&W[(size_t)(k0 + r) * ND + n0 + c];
    tile[r][c] = v.x; tile[r][c + 1] = v.y;
    tile[r][c + 2] = v.z; tile[r][c + 3] = v.w;
  }
  __syncthreads();
#pragma unroll
  for (int i = 0; i < 4; ++i) {
    int n = (t >> 4) + i * 16;
    int kc = (t & 15) * 4;
    bf16x4 o;
#pragma unroll
    for (int j = 0; j < 4; ++j) o[j] = f2b(tile[kc + j][n]);
    *(bf16x4*)&T[(size_t)(n0 + n) * ND + k0 + kc] = o;
  }
}

// ---------------------------------------------------------------------------
// MFMA bf16 GEMM core: C = A[M,512] @ Bt[512,512]^T, 128x64 tile (M x N),
// BK=64, DOUBLE-BUFFERED global_load_lds staging (1 barrier/iter, DMA for
// tile i+1 in flight across the compute of tile i).  XOR-swizzled LDS
// (pitch 64 shorts, chunk ^= row&7).  4 waves, each 64x32 output.
// mode 0: fp32 row-major out; 1: bf16 row-major out; 2: bf16 V^T out.
// ---------------------------------------------------------------------------
__device__ __forceinline__ void gemm_core(const short* __restrict__ A,
                                          const short* __restrict__ Bt,
                                          void* __restrict__ Cout, int mode,
                                          float alpha) {
  __shared__ short As[2][128 * 64];
  __shared__ short Bs[2][64 * 64];
  const int t = threadIdx.x;
  const int wave = t >> 6, lane = t & 63;
  const int m = lane & 15, quad = lane >> 4;
  const int m0 = blockIdx.y * 128, n0 = blockIdx.x * 64;
  const int mh = (wave >> 1) * 64, nh = (wave & 1) * 32;
  const int r8 = lane >> 3;        // 0..7: row within wave's staging band
  const int c8 = (lane & 7) ^ r8;  // swizzled global chunk for this lane
  const int mx7 = m & 7;           // fragment-read swizzle key
  f32x4 acc[4][2];
#pragma unroll
  for (int i = 0; i < 4; ++i)
#pragma unroll
    for (int j = 0; j < 2; ++j) acc[i][j] = (f32x4){0.f, 0.f, 0.f, 0.f};

  // prefetch k-tile 0 into buffer 0
#pragma unroll
  for (int i = 0; i < 4; ++i)
    dma16(A + (size_t)(m0 + i * 32 + wave * 8 + r8) * ND + c8 * 8,
          As[0] + (i * 256 + wave * 64) * 8);
#pragma unroll
  for (int i = 0; i < 2; ++i)
    dma16(Bt + (size_t)(n0 + i * 32 + wave * 8 + r8) * ND + c8 * 8,
          Bs[0] + (i * 256 + wave * 64) * 8);

  int buf = 0;
  for (int k0 = 0; k0 < ND; k0 += 64, buf ^= 1) {
    __syncthreads();  // drains DMA(buf); prior readers of buf^1 done
    if (k0 + 64 < ND) {
#pragma unroll
      for (int i = 0; i < 4; ++i)
        dma16(A + (size_t)(m0 + i * 32 + wave * 8 + r8) * ND + k0 + 64 + c8 * 8,
              As[buf ^ 1] + (i * 256 + wave * 64) * 8);
#pragma unroll
      for (int i = 0; i < 2; ++i)
        dma16(Bt + (size_t)(n0 + i * 32 + wave * 8 + r8) * ND + k0 + 64 +
                  c8 * 8,
              Bs[buf ^ 1] + (i * 256 + wave * 64) * 8);
    }
    bf16x8 af[4][2], bf[2][2];
#pragma unroll
    for (int mt = 0; mt < 4; ++mt)
#pragma unroll
      for (int kc = 0; kc < 2; ++kc)
        af[mt][kc] = *(const bf16x8*)(As[buf] + (mh + mt * 16 + m) * 64 +
                                      ((kc * 4 + quad) ^ mx7) * 8);
#pragma unroll
    for (int nt = 0; nt < 2; ++nt)
#pragma unroll
      for (int kc = 0; kc < 2; ++kc)
        bf[nt][kc] = *(const bf16x8*)(Bs[buf] + (nh + nt * 16 + m) * 64 +
                                      ((kc * 4 + quad) ^ mx7) * 8);
#pragma unroll
    for (int mt = 0; mt < 4; ++mt)
#pragma unroll
      for (int nt = 0; nt < 2; ++nt)
#pragma unroll
        for (int kc = 0; kc < 2; ++kc)
          acc[mt][nt] = __builtin_amdgcn_mfma_f32_16x16x32_bf16(
              af[mt][kc], bf[nt][kc], acc[mt][nt], 0, 0, 0);
  }
  if (mode == 2) {
    // V^T scatter: value at (token row, channel col) -> Vt[b][h][d][s]
#pragma unroll
    for (int mt = 0; mt < 4; ++mt)
#pragma unroll
      for (int nt = 0; nt < 2; ++nt) {
        int row0 = m0 + mh + mt * 16 + quad * 4;
        int col = n0 + nh + nt * 16 + m;
        int b_ = row0 >> 11, s_ = row0 & (NS - 1);
        int h_ = col >> 6, d_ = col & (DEP - 1);
        uint2 p;
        p.x = pk2(acc[mt][nt][0] * alpha, acc[mt][nt][1] * alpha);
        p.y = pk2(acc[mt][nt][2] * alpha, acc[mt][nt][3] * alpha);
        *(uint2*)((short*)Cout +
                  (size_t)((b_ * NH + h_) * DEP + d_) * NS + s_) = p;
      }
  } else {
#pragma unroll
    for (int mt = 0; mt < 4; ++mt)
#pragma unroll
      for (int nt = 0; nt < 2; ++nt)
#pragma unroll
        for (int r = 0; r < 4; ++r) {
          int row = m0 + mh + mt * 16 + quad * 4 + r;
          int col = n0 + nh + nt * 16 + m;
          float v = acc[mt][nt][r] * alpha;
          if (mode == 1)
            ((short*)Cout)[(size_t)row * ND + col] = f2b(v);
          else
            ((float*)Cout)[(size_t)row * ND + col] = v;
        }
  }
}

__global__ __launch_bounds__(256) void qkv_gemm(
    const short* __restrict__ xb, const short* __restrict__ yb,
    const short* __restrict__ Wqt, const short* __restrict__ Wkt,
    const short* __restrict__ Wvt, short* __restrict__ Qb,
    short* __restrict__ Kb, short* __restrict__ Vtb) {
  if (blockIdx.z == 0)
    gemm_core(xb, Wqt, Qb, 1, QSCALE);  // scale + log2e folded into Q
  else if (blockIdx.z == 1)
    gemm_core(yb, Wkt, Kb, 1, 1.0f);
  else
    gemm_core(yb, Wvt, Vtb, 2, 1.0f);
}

__global__ __launch_bounds__(256) void out_gemm(const short* __restrict__ Ab,
                                                const short* __restrict__ Wot,
                                                float* __restrict__ out) {
  gemm_core(Ab, Wot, out, 0, 1.0f);
}

// ---------------------------------------------------------------------------
// Flash attention, S^T formulation, max-free softmax, DOUBLE-BUFFERED K/V
// DMA (1 barrier/iter).  Block = 128 q x (b,h), 4 waves x 32 q.
// ---------------------------------------------------------------------------
__global__ __launch_bounds__(256) void attn_mfma(const short* __restrict__ Qb,
                                                 const short* __restrict__ Kb,
                                                 const short* __restrict__ Vtb,
                                                 short* __restrict__ Ob) {
  __shared__ short Ks[2][64 * 64];   // [kv][d], swizzled
  __shared__ short Vts[2][64 * 64];  // [d][kv], swizzled
  __shared__ short Pt[128 * 64];     // [q][kv], swizzled, wave-private bands
  const int t = threadIdx.x;
  const int wave = t >> 6, lane = t & 63;
  const int m = lane & 15, quad = lane >> 4;
  const int bh = blockIdx.y, b = bh >> 3, h = bh & 7;
  const int q0 = blockIdx.x * 128;
  const int wq = wave * 32;
  const size_t rowb = (size_t)b * NS;
  const short* Vtbase = Vtb + (size_t)(bh * DEP) * NS;
  const int r8 = lane >> 3;
  const int c8 = (lane & 7) ^ r8;
  const int mx7 = m & 7;

  // Q fragments (B-operand), register-resident
  bf16x8 qf[2][2];
#pragma unroll
  for (int nt = 0; nt < 2; ++nt)
#pragma unroll
    for (int kc = 0; kc < 2; ++kc)
      qf[nt][kc] = *(const bf16x8*)(Qb + (rowb + q0 + wq + nt * 16 + m) * ND +
                                    h * DEP + kc * 32 + quad * 8);

  float l_[2] = {0.0f, 0.0f};  // per-lane partial row sums
  f32x4 Ot[4][2];              // O^T [d=64][q=32] in C layout
#pragma unroll
  for (int mt = 0; mt < 4; ++mt)
#pragma unroll
    for (int nt = 0; nt < 2; ++nt) Ot[mt][nt] = (f32x4){0.f, 0.f, 0.f, 0.f};

  // prefetch kv-tile 0 into buffer 0
#pragma unroll
  for (int i = 0; i < 2; ++i) {
    int row = i * 32 + wave * 8 + r8;
    dma16(Kb + (rowb + row) * ND + h * DEP + c8 * 8,
          Ks[0] + (i * 256 + wave * 64) * 8);
    dma16(Vtbase + (size_t)row * NS + c8 * 8,
          Vts[0] + (i * 256 + wave * 64) * 8);
  }

  int buf = 0;
  for (int kv0 = 0; kv0 < NS; kv0 += 64, buf ^= 1) {
    __syncthreads();  // drains DMA(buf); prior readers of buf^1 done
    if (kv0 + 64 < NS) {
#pragma unroll
      for (int i = 0; i < 2; ++i) {
        int row = i * 32 + wave * 8 + r8;
        dma16(Kb + (rowb + kv0 + 64 + row) * ND + h * DEP + c8 * 8,
              Ks[buf ^ 1] + (i * 256 + wave * 64) * 8);
        dma16(Vtbase + (size_t)row * NS + kv0 + 64 + c8 * 8,
              Vts[buf ^ 1] + (i * 256 + wave * 64) * 8);
      }
    }

    // S^T = K . Q^T  (A = K rows, B = Q rows)
    f32x4 St[4][2];
#pragma unroll
    for (int mt = 0; mt < 4; ++mt)
#pragma unroll
      for (int nt = 0; nt < 2; ++nt) St[mt][nt] = (f32x4){0.f, 0.f, 0.f, 0.f};
#pragma unroll
    for (int mt = 0; mt < 4; ++mt)
#pragma unroll
      for (int kc = 0; kc < 2; ++kc) {
        bf16x8 kf = *(const bf16x8*)(Ks[buf] + (mt * 16 + m) * 64 +
                                     ((kc * 4 + quad) ^ mx7) * 8);
#pragma unroll
        for (int nt = 0; nt < 2; ++nt)
          St[mt][nt] = __builtin_amdgcn_mfma_f32_16x16x32_bf16(
              kf, qf[nt][kc], St[mt][nt], 0, 0, 0);
      }

    // max-free softmax: p = exp2(S'), accumulate per-lane partial l,
    // pack P^T (C layout [kv][q]) -> swizzled Pt[q][kv], 4 kv per b64
#pragma unroll
    for (int nt = 0; nt < 2; ++nt) {
      float rs = 0.0f;
#pragma unroll
      for (int mt = 0; mt < 4; ++mt) {
        float p0 = exp2f(St[mt][nt][0]);
        float p1 = exp2f(St[mt][nt][1]);
        float p2 = exp2f(St[mt][nt][2]);
        float p3 = exp2f(St[mt][nt][3]);
        rs += (p0 + p1) + (p2 + p3);
        uint2 pk;
        pk.x = pk2(p0, p1);
        pk.y = pk2(p2, p3);
        *(uint2*)(Pt + (wq + nt * 16 + m) * 64 +
                  ((mt * 2 + (quad >> 1)) ^ mx7) * 8 + (quad & 1) * 4) = pk;
      }
      l_[nt] += rs;
    }

    // O^T += V^T . P^T  (A = V^T rows from LDS, B = P rows)
#pragma unroll
    for (int kc = 0; kc < 2; ++kc) {
      bf16x8 pf[2];
#pragma unroll
      for (int nt = 0; nt < 2; ++nt)
        pf[nt] = *(const bf16x8*)(Pt + (wq + nt * 16 + m) * 64 +
                                  ((kc * 4 + quad) ^ mx7) * 8);
#pragma unroll
      for (int mt = 0; mt < 4; ++mt) {
        bf16x8 vf = *(const bf16x8*)(Vts[buf] + (mt * 16 + m) * 64 +
                                     ((kc * 4 + quad) ^ mx7) * 8);
#pragma unroll
        for (int nt = 0; nt < 2; ++nt)
          Ot[mt][nt] = __builtin_amdgcn_mfma_f32_16x16x32_bf16(
              vf, pf[nt], Ot[mt][nt], 0, 0, 0);
      }
    }
  }

  // epilogue: reduce l across the 4 lane-groups, normalize, store
#pragma unroll
  for (int nt = 0; nt < 2; ++nt) {
    l_[nt] += __shfl_xor(l_[nt], 16, 64);
    l_[nt] += __shfl_xor(l_[nt], 32, 64);
    float linv = 1.0f / l_[nt];
    size_t row = rowb + q0 + wq + nt * 16 + m;
#pragma unroll
    for (int mt = 0; mt < 4; ++mt)
#pragma unroll
      for (int r = 0; r < 4; ++r)
        Ob[row * ND + h * DEP + mt * 16 + quad * 4 + r] =
            f2b(Ot[mt][nt][r] * linv);
  }
}

// ---------------------------------------------------------------------------
extern "C" void kernel_launch(void* const* d_in, const int* in_sizes, int n_in,
                              void* d_out, int out_size, void* d_ws,
                              size_t ws_size, hipStream_t stream) {
  const float* x = (const float*)d_in[0];
  const float* y = (const float*)d_in[1];
  const float* Wq = (const float*)d_in[2];
  const float* Wk = (const float*)d_in[3];
  const float* Wv = (const float*)d_in[4];
  const float* Wo = (const float*)d_in[5];
  float* out = (float*)d_out;

  const size_t mat = (size_t)NB * NS * ND;
  const size_t wsz = (size_t)ND * ND;
  short* xb = (short*)d_ws;
  short* yb = xb + mat;
  short* Wqt = yb + mat;
  short* Wkt = Wqt + wsz;
  short* Wvt = Wkt + wsz;
  short* Wot = Wvt + wsz;
  short* Qb = Wot + wsz;
  short* Kb = Qb + mat;
  short* Vtb = Kb + mat;
  short* attnb = xb;  // reuse: xb dead after QKV GEMM

  cast_xy<<<dim3(mat / 1024, 2), 256, 0, stream>>>(x, y, xb, yb);
  trans_w<<<dim3(8, 8, 4), 256, 0, stream>>>(Wq, Wk, Wv, Wo, Wqt, Wkt, Wvt,
                                             Wot);
  qkv_gemm<<<dim3(ND / 64, (NB * NS) / 128, 3), 256, 0, stream>>>(
      xb, yb, Wqt, Wkt, Wvt, Qb, Kb, Vtb);
  attn_mfma<<<dim3(NS / 128, NB * NH), 256, 0, stream>>>(Qb, Kb, Vtb, attnb);
  out_gemm<<<dim3(ND / 64, (NB * NS) / 128), 256, 0, stream>>>(attnb, Wot,
                                                               out);
}

// Round 7
// 192.183 us; speedup vs baseline: 1.0668x; 1.0668x over previous
//
#include <hip/hip_runtime.h>
#include <hip/hip_bf16.h>
#include <math.h>
#include <stdint.h>

#define NB 4
#define NS 2048
#define ND 512
#define NH 8
#define DEP 64

typedef __attribute__((ext_vector_type(8))) short bf16x8;
typedef __attribute__((ext_vector_type(4))) short bf16x4;
typedef __attribute__((ext_vector_type(4))) float f32x4;

#define QSCALE 0.18033688011112042f  // DEPTH^-0.5 * log2(e): softmax in exp2

__device__ __forceinline__ short f2b(float f) {
  unsigned u = __float_as_uint(f);
  u += 0x7FFF + ((u >> 16) & 1);  // RNE
  return (short)(u >> 16);
}
__device__ __forceinline__ unsigned pk2(float a, float b) {
  union { __hip_bfloat162 h; unsigned u; } c;
  c.h = __float22bfloat162_rn(float2{a, b});
  return c.u;
}
// async 16B global->LDS DMA; LDS dest is wave-uniform base + lane*16
__device__ __forceinline__ void dma16(const void* g, void* l) {
  __builtin_amdgcn_global_load_lds(
      (const __attribute__((address_space(1))) void*)g,
      (__attribute__((address_space(3))) void*)l, 16, 0, 0);
}

// ---------------------------------------------------------------------------
__global__ __launch_bounds__(256) void cast_xy(const float* __restrict__ x,
                                               const float* __restrict__ y,
                                               short* __restrict__ xb,
                                               short* __restrict__ yb) {
  const float* src = blockIdx.y ? y : x;
  short* dst = blockIdx.y ? yb : xb;
  size_t i = ((size_t)blockIdx.x * 256 + threadIdx.x) * 4;
  float4 v = *(const float4*)(src + i);
  bf16x4 o;
  o[0] = f2b(v.x); o[1] = f2b(v.y); o[2] = f2b(v.z); o[3] = f2b(v.w);
  *(bf16x4*)(dst + i) = o;
}

// ---------------------------------------------------------------------------
// transpose + cast W[512][512] fp32 -> Wt[512][512] bf16 (Wt[n][k] = W[k][n])
// ---------------------------------------------------------------------------
__global__ __launch_bounds__(256) void trans_w(
    const float* __restrict__ W0, const float* __restrict__ W1,
    const float* __restrict__ W2, const float* __restrict__ W3,
    short* __restrict__ T0, short* __restrict__ T1, short* __restrict__ T2,
    short* __restrict__ T3) {
  const float* W = blockIdx.z == 0 ? W0 : blockIdx.z == 1 ? W1
                   : blockIdx.z == 2 ? W2 : W3;
  short* T = blockIdx.z == 0 ? T0 : blockIdx.z == 1 ? T1
             : blockIdx.z == 2 ? T2 : T3;
  __shared__ float tile[64][65];
  const int t = threadIdx.x;
  const int k0 = blockIdx.x * 64, n0 = blockIdx.y * 64;
#pragma unroll
  for (int i = 0; i < 4; ++i) {
    int r = (t >> 4) + i * 16;
    int c = (t & 15) * 4;
    float4 v = *(const float4*)&W[(size_t)(k0 + r) * ND + n0 + c];
    tile[r][c] = v.x; tile[r][c + 1] = v.y;
    tile[r][c + 2] = v.z; tile[r][c + 3] = v.w;
  }
  __syncthreads();
#pragma unroll
  for (int i = 0; i < 4; ++i) {
    int n = (t >> 4) + i * 16;
    int kc = (t & 15) * 4;
    bf16x4 o;
#pragma unroll
    for (int j = 0; j < 4; ++j) o[j] = f2b(tile[kc + j][n]);
    *(bf16x4*)&T[(size_t)(n0 + n) * ND + k0 + kc] = o;
  }
}

// ---------------------------------------------------------------------------
// MFMA bf16 GEMM core: C = A[M,512] @ Bt[512,512]^T, 128x64 tile (M x N),
// BK=64, double-buffered global_load_lds staging, XOR-swizzled LDS.
// mode 0: fp32 row-major out; 1: bf16 row-major out; 2: bf16 V^T out.
// ---------------------------------------------------------------------------
__device__ __forceinline__ void gemm_core(const short* __restrict__ A,
                                          const short* __restrict__ Bt,
                                          void* __restrict__ Cout, int mode,
                                          float alpha) {
  __shared__ short As[2][128 * 64];
  __shared__ short Bs[2][64 * 64];
  const int t = threadIdx.x;
  const int wave = t >> 6, lane = t & 63;
  const int m = lane & 15, quad = lane >> 4;
  const int m0 = blockIdx.y * 128, n0 = blockIdx.x * 64;
  const int mh = (wave >> 1) * 64, nh = (wave & 1) * 32;
  const int r8 = lane >> 3;        // 0..7: row within wave's staging band
  const int c8 = (lane & 7) ^ r8;  // swizzled global chunk for this lane
  const int mx7 = m & 7;           // fragment-read swizzle key
  f32x4 acc[4][2];
#pragma unroll
  for (int i = 0; i < 4; ++i)
#pragma unroll
    for (int j = 0; j < 2; ++j) acc[i][j] = (f32x4){0.f, 0.f, 0.f, 0.f};

  // prefetch k-tile 0 into buffer 0
#pragma unroll
  for (int i = 0; i < 4; ++i)
    dma16(A + (size_t)(m0 + i * 32 + wave * 8 + r8) * ND + c8 * 8,
          As[0] + (i * 256 + wave * 64) * 8);
#pragma unroll
  for (int i = 0; i < 2; ++i)
    dma16(Bt + (size_t)(n0 + i * 32 + wave * 8 + r8) * ND + c8 * 8,
          Bs[0] + (i * 256 + wave * 64) * 8);

  int buf = 0;
  for (int k0 = 0; k0 < ND; k0 += 64, buf ^= 1) {
    __syncthreads();  // drains DMA(buf); prior readers of buf^1 done
    if (k0 + 64 < ND) {
#pragma unroll
      for (int i = 0; i < 4; ++i)
        dma16(A + (size_t)(m0 + i * 32 + wave * 8 + r8) * ND + k0 + 64 + c8 * 8,
              As[buf ^ 1] + (i * 256 + wave * 64) * 8);
#pragma unroll
      for (int i = 0; i < 2; ++i)
        dma16(Bt + (size_t)(n0 + i * 32 + wave * 8 + r8) * ND + k0 + 64 +
                  c8 * 8,
              Bs[buf ^ 1] + (i * 256 + wave * 64) * 8);
    }
    bf16x8 af[4][2], bf[2][2];
#pragma unroll
    for (int mt = 0; mt < 4; ++mt)
#pragma unroll
      for (int kc = 0; kc < 2; ++kc)
        af[mt][kc] = *(const bf16x8*)(As[buf] + (mh + mt * 16 + m) * 64 +
                                      ((kc * 4 + quad) ^ mx7) * 8);
#pragma unroll
    for (int nt = 0; nt < 2; ++nt)
#pragma unroll
      for (int kc = 0; kc < 2; ++kc)
        bf[nt][kc] = *(const bf16x8*)(Bs[buf] + (nh + nt * 16 + m) * 64 +
                                      ((kc * 4 + quad) ^ mx7) * 8);
#pragma unroll
    for (int mt = 0; mt < 4; ++mt)
#pragma unroll
      for (int nt = 0; nt < 2; ++nt)
#pragma unroll
        for (int kc = 0; kc < 2; ++kc)
          acc[mt][nt] = __builtin_amdgcn_mfma_f32_16x16x32_bf16(
              af[mt][kc], bf[nt][kc], acc[mt][nt], 0, 0, 0);
  }
  if (mode == 2) {
    // V^T scatter: value at (token row, channel col) -> Vt[b][h][d][s]
#pragma unroll
    for (int mt = 0; mt < 4; ++mt)
#pragma unroll
      for (int nt = 0; nt < 2; ++nt) {
        int row0 = m0 + mh + mt * 16 + quad * 4;
        int col = n0 + nh + nt * 16 + m;
        int b_ = row0 >> 11, s_ = row0 & (NS - 1);
        int h_ = col >> 6, d_ = col & (DEP - 1);
        uint2 p;
        p.x = pk2(acc[mt][nt][0] * alpha, acc[mt][nt][1] * alpha);
        p.y = pk2(acc[mt][nt][2] * alpha, acc[mt][nt][3] * alpha);
        *(uint2*)((short*)Cout +
                  (size_t)((b_ * NH + h_) * DEP + d_) * NS + s_) = p;
      }
  } else {
#pragma unroll
    for (int mt = 0; mt < 4; ++mt)
#pragma unroll
      for (int nt = 0; nt < 2; ++nt)
#pragma unroll
        for (int r = 0; r < 4; ++r) {
          int row = m0 + mh + mt * 16 + quad * 4 + r;
          int col = n0 + nh + nt * 16 + m;
          float v = acc[mt][nt][r] * alpha;
          if (mode == 1)
            ((short*)Cout)[(size_t)row * ND + col] = f2b(v);
          else
            ((float*)Cout)[(size_t)row * ND + col] = v;
        }
  }
}

__global__ __launch_bounds__(256) void qkv_gemm(
    const short* __restrict__ xb, const short* __restrict__ yb,
    const short* __restrict__ Wqt, const short* __restrict__ Wkt,
    const short* __restrict__ Wvt, short* __restrict__ Qb,
    short* __restrict__ Kb, short* __restrict__ Vtb) {
  if (blockIdx.z == 0)
    gemm_core(xb, Wqt, Qb, 1, QSCALE);  // scale + log2e folded into Q
  else if (blockIdx.z == 1)
    gemm_core(yb, Wkt, Kb, 1, 1.0f);
  else
    gemm_core(yb, Wvt, Vtb, 2, 1.0f);
}

__global__ __launch_bounds__(256) void out_gemm(const short* __restrict__ Ab,
                                                const short* __restrict__ Wot,
                                                float* __restrict__ out) {
  gemm_core(Ab, Wot, out, 0, 1.0f);
}

// ---------------------------------------------------------------------------
// Flash attention, S^T formulation, max-free softmax (raw v_exp_f32).
// Block = 64 q x (b,h), 4 waves x 16 q => grid 1024 blocks, LDS 40960 B
// => 4 blocks/CU, 4 waves/SIMD (was 2).  Double-buffered K/V DMA.
// ---------------------------------------------------------------------------
__global__ __launch_bounds__(256) void attn_mfma(const short* __restrict__ Qb,
                                                 const short* __restrict__ Kb,
                                                 const short* __restrict__ Vtb,
                                                 short* __restrict__ Ob) {
  __shared__ short Ks[2][64 * 64];   // [kv][d], swizzled
  __shared__ short Vts[2][64 * 64];  // [d][kv], swizzled
  __shared__ short Pt[64 * 64];      // [q][kv], swizzled, wave-private bands
  const int t = threadIdx.x;
  const int wave = t >> 6, lane = t & 63;
  const int m = lane & 15, quad = lane >> 4;
  const int bh = blockIdx.y, b = bh >> 3, h = bh & 7;
  const int q0 = blockIdx.x * 64;
  const int wq = wave * 16;
  const size_t rowb = (size_t)b * NS;
  const short* Vtbase = Vtb + (size_t)(bh * DEP) * NS;
  const int r8 = lane >> 3;
  const int c8 = (lane & 7) ^ r8;
  const int mx7 = m & 7;

  // Q fragments (B-operand), register-resident: wave's 16 q rows
  bf16x8 qf[2];
#pragma unroll
  for (int kc = 0; kc < 2; ++kc)
    qf[kc] = *(const bf16x8*)(Qb + (rowb + q0 + wq + m) * ND + h * DEP +
                              kc * 32 + quad * 8);

  float l_ = 0.0f;  // per-lane partial row sum
  f32x4 Ot[4];      // O^T [d=64][q=16] in C layout
#pragma unroll
  for (int mt = 0; mt < 4; ++mt) Ot[mt] = (f32x4){0.f, 0.f, 0.f, 0.f};

  // prefetch kv-tile 0 into buffer 0
#pragma unroll
  for (int i = 0; i < 2; ++i) {
    int row = i * 32 + wave * 8 + r8;
    dma16(Kb + (rowb + row) * ND + h * DEP + c8 * 8,
          Ks[0] + (i * 256 + wave * 64) * 8);
    dma16(Vtbase + (size_t)row * NS + c8 * 8,
          Vts[0] + (i * 256 + wave * 64) * 8);
  }

  int buf = 0;
  for (int kv0 = 0; kv0 < NS; kv0 += 64, buf ^= 1) {
    __syncthreads();  // drains DMA(buf); prior readers of buf^1 done
    if (kv0 + 64 < NS) {
#pragma unroll
      for (int i = 0; i < 2; ++i) {
        int row = i * 32 + wave * 8 + r8;
        dma16(Kb + (rowb + kv0 + 64 + row) * ND + h * DEP + c8 * 8,
              Ks[buf ^ 1] + (i * 256 + wave * 64) * 8);
        dma16(Vtbase + (size_t)row * NS + kv0 + 64 + c8 * 8,
              Vts[buf ^ 1] + (i * 256 + wave * 64) * 8);
      }
    }

    // S^T = K . Q^T  (A = K rows, B = Q rows; 64 kv x 16 q per wave)
    f32x4 St[4];
#pragma unroll
    for (int mt = 0; mt < 4; ++mt) St[mt] = (f32x4){0.f, 0.f, 0.f, 0.f};
#pragma unroll
    for (int mt = 0; mt < 4; ++mt)
#pragma unroll
      for (int kc = 0; kc < 2; ++kc) {
        bf16x8 kf = *(const bf16x8*)(Ks[buf] + (mt * 16 + m) * 64 +
                                     ((kc * 4 + quad) ^ mx7) * 8);
        St[mt] = __builtin_amdgcn_mfma_f32_16x16x32_bf16(kf, qf[kc], St[mt],
                                                         0, 0, 0);
      }

    // max-free softmax: p = exp2(S') via raw v_exp_f32 (no denorm guard;
    // flush-to-zero is correct for softmax tails)
    float rs = 0.0f;
#pragma unroll
    for (int mt = 0; mt < 4; ++mt) {
      float p0 = __builtin_amdgcn_exp2f(St[mt][0]);
      float p1 = __builtin_amdgcn_exp2f(St[mt][1]);
      float p2 = __builtin_amdgcn_exp2f(St[mt][2]);
      float p3 = __builtin_amdgcn_exp2f(St[mt][3]);
      rs += (p0 + p1) + (p2 + p3);
      uint2 pk;
      pk.x = pk2(p0, p1);
      pk.y = pk2(p2, p3);
      *(uint2*)(Pt + (wq + m) * 64 + ((mt * 2 + (quad >> 1)) ^ mx7) * 8 +
                (quad & 1) * 4) = pk;
    }
    l_ += rs;

    // O^T += V^T . P^T  (A = V^T rows from LDS, B = P rows)
#pragma unroll
    for (int kc = 0; kc < 2; ++kc) {
      bf16x8 pf = *(const bf16x8*)(Pt + (wq + m) * 64 +
                                   ((kc * 4 + quad) ^ mx7) * 8);
#pragma unroll
      for (int mt = 0; mt < 4; ++mt) {
        bf16x8 vf = *(const bf16x8*)(Vts[buf] + (mt * 16 + m) * 64 +
                                     ((kc * 4 + quad) ^ mx7) * 8);
        Ot[mt] = __builtin_amdgcn_mfma_f32_16x16x32_bf16(vf, pf, Ot[mt],
                                                         0, 0, 0);
      }
    }
  }

  // epilogue: reduce l across the 4 lane-groups, normalize, store
  l_ += __shfl_xor(l_, 16, 64);
  l_ += __shfl_xor(l_, 32, 64);
  float linv = 1.0f / l_;
  size_t row = rowb + q0 + wq + m;
#pragma unroll
  for (int mt = 0; mt < 4; ++mt)
#pragma unroll
    for (int r = 0; r < 4; ++r)
      Ob[row * ND + h * DEP + mt * 16 + quad * 4 + r] = f2b(Ot[mt][r] * linv);
}

// ---------------------------------------------------------------------------
extern "C" void kernel_launch(void* const* d_in, const int* in_sizes, int n_in,
                              void* d_out, int out_size, void* d_ws,
                              size_t ws_size, hipStream_t stream) {
  const float* x = (const float*)d_in[0];
  const float* y = (const float*)d_in[1];
  const float* Wq = (const float*)d_in[2];
  const float* Wk = (const float*)d_in[3];
  const float* Wv = (const float*)d_in[4];
  const float* Wo = (const float*)d_in[5];
  float* out = (float*)d_out;

  const size_t mat = (size_t)NB * NS * ND;
  const size_t wsz = (size_t)ND * ND;
  short* xb = (short*)d_ws;
  short* yb = xb + mat;
  short* Wqt = yb + mat;
  short* Wkt = Wqt + wsz;
  short* Wvt = Wkt + wsz;
  short* Wot = Wvt + wsz;
  short* Qb = Wot + wsz;
  short* Kb = Qb + mat;
  short* Vtb = Kb + mat;
  short* attnb = xb;  // reuse: xb dead after QKV GEMM

  cast_xy<<<dim3(mat / 1024, 2), 256, 0, stream>>>(x, y, xb, yb);
  trans_w<<<dim3(8, 8, 4), 256, 0, stream>>>(Wq, Wk, Wv, Wo, Wqt, Wkt, Wvt,
                                             Wot);
  qkv_gemm<<<dim3(ND / 64, (NB * NS) / 128, 3), 256, 0, stream>>>(
      xb, yb, Wqt, Wkt, Wvt, Qb, Kb, Vtb);
  attn_mfma<<<dim3(NS / 64, NB * NH), 256, 0, stream>>>(Qb, Kb, Vtb, attnb);
  out_gemm<<<dim3(ND / 64, (NB * NS) / 128), 256, 0, stream>>>(attnb, Wot,
                                                               out);
}

// Round 8
// 186.439 us; speedup vs baseline: 1.0997x; 1.0308x over previous
//
#include <hip/hip_runtime.h>
#include <hip/hip_bf16.h>
#include <math.h>
#include <stdint.h>

#define NB 4
#define NS 2048
#define ND 512
#define NH 8
#define DEP 64

typedef __attribute__((ext_vector_type(8))) short bf16x8;
typedef __attribute__((ext_vector_type(4))) short bf16x4;
typedef __attribute__((ext_vector_type(4))) float f32x4;

#define QSCALE 0.18033688011112042f  // DEPTH^-0.5 * log2(e): softmax in exp2

__device__ __forceinline__ short f2b(float f) {
  unsigned u = __float_as_uint(f);
  u += 0x7FFF + ((u >> 16) & 1);  // RNE
  return (short)(u >> 16);
}
__device__ __forceinline__ unsigned pk2(float a, float b) {
  union { __hip_bfloat162 h; unsigned u; } c;
  c.h = __float22bfloat162_rn(float2{a, b});
  return c.u;
}
// async 16B global->LDS DMA; LDS dest is wave-uniform base + lane*16
__device__ __forceinline__ void dma16(const void* g, void* l) {
  __builtin_amdgcn_global_load_lds(
      (const __attribute__((address_space(1))) void*)g,
      (__attribute__((address_space(3))) void*)l, 16, 0, 0);
}

// ---------------------------------------------------------------------------
// prep: one launch does BOTH input casts and all 4 weight transposes.
// grid (4096, 3): y=0 cast x, y=1 cast y, y=2 (x<256) transpose W0..W3.
// ---------------------------------------------------------------------------
__global__ __launch_bounds__(256) void prep(
    const float* __restrict__ x, const float* __restrict__ y,
    const float* __restrict__ W0, const float* __restrict__ W1,
    const float* __restrict__ W2, const float* __restrict__ W3,
    short* __restrict__ xb, short* __restrict__ yb, short* __restrict__ T0,
    short* __restrict__ T1, short* __restrict__ T2, short* __restrict__ T3) {
  const int t = threadIdx.x;
  if (blockIdx.y < 2) {
    const float* src = blockIdx.y ? y : x;
    short* dst = blockIdx.y ? yb : xb;
    size_t i = ((size_t)blockIdx.x * 256 + t) * 4;
    float4 v = *(const float4*)(src + i);
    bf16x4 o;
    o[0] = f2b(v.x); o[1] = f2b(v.y); o[2] = f2b(v.z); o[3] = f2b(v.w);
    *(bf16x4*)(dst + i) = o;
    return;
  }
  const int bx = blockIdx.x;
  if (bx >= 256) return;
  const int wj = bx >> 6, rem = bx & 63;
  const float* W = wj == 0 ? W0 : wj == 1 ? W1 : wj == 2 ? W2 : W3;
  short* T = wj == 0 ? T0 : wj == 1 ? T1 : wj == 2 ? T2 : T3;
  __shared__ float tile[64][65];
  const int k0 = (rem >> 3) * 64, n0 = (rem & 7) * 64;
#pragma unroll
  for (int i = 0; i < 4; ++i) {
    int r = (t >> 4) + i * 16;
    int c = (t & 15) * 4;
    float4 v = *(const float4*)&W[(size_t)(k0 + r) * ND + n0 + c];
    tile[r][c] = v.x; tile[r][c + 1] = v.y;
    tile[r][c + 2] = v.z; tile[r][c + 3] = v.w;
  }
  __syncthreads();
#pragma unroll
  for (int i = 0; i < 4; ++i) {
    int n = (t >> 4) + i * 16;
    int kc = (t & 15) * 4;
    bf16x4 o;
#pragma unroll
    for (int j = 0; j < 4; ++j) o[j] = f2b(tile[kc + j][n]);
    *(bf16x4*)&T[(size_t)(n0 + n) * ND + k0 + kc] = o;
  }
}

// ---------------------------------------------------------------------------
// QKV GEMM: 128x128 tile, 4 waves each 64x64 (acc 4x4), BK=64, single-buffer
// DMA staging (m97 2-barrier), XOR-swizzled LDS (pitch 64, chunk ^= row&7).
// 32 KB LDS -> 3 blocks/CU at grid 768.  High intensity: 32 flops/LDS-byte.
// mode 1: bf16 row-major out; 2: bf16 V^T out.
// ---------------------------------------------------------------------------
__device__ __forceinline__ void gemm128(const short* __restrict__ A,
                                        const short* __restrict__ Bt,
                                        short* __restrict__ Cout, int mode,
                                        float alpha) {
  __shared__ short As[128 * 64];
  __shared__ short Bs[128 * 64];
  const int t = threadIdx.x;
  const int wave = t >> 6, lane = t & 63;
  const int m = lane & 15, quad = lane >> 4;
  const int m0 = blockIdx.y * 128, n0 = blockIdx.x * 128;
  const int mh = (wave >> 1) * 64, nh = (wave & 1) * 64;
  const int r8 = lane >> 3;        // 0..7: row within wave's staging band
  const int c8 = (lane & 7) ^ r8;  // swizzled global chunk for this lane
  const int mx7 = m & 7;           // fragment-read swizzle key
  f32x4 acc[4][4];
#pragma unroll
  for (int i = 0; i < 4; ++i)
#pragma unroll
    for (int j = 0; j < 4; ++j) acc[i][j] = (f32x4){0.f, 0.f, 0.f, 0.f};

  for (int k0 = 0; k0 < ND; k0 += 64) {
    __syncthreads();  // prior iteration's fragment readers done
#pragma unroll
    for (int i = 0; i < 4; ++i) {
      int row = i * 32 + wave * 8 + r8;
      dma16(A + (size_t)(m0 + row) * ND + k0 + c8 * 8,
            As + (i * 256 + wave * 64) * 8);
      dma16(Bt + (size_t)(n0 + row) * ND + k0 + c8 * 8,
            Bs + (i * 256 + wave * 64) * 8);
    }
    __syncthreads();  // drains vmcnt: all DMA visible
    bf16x8 af[4][2], bf[4][2];
#pragma unroll
    for (int mt = 0; mt < 4; ++mt)
#pragma unroll
      for (int kc = 0; kc < 2; ++kc)
        af[mt][kc] = *(const bf16x8*)(As + (mh + mt * 16 + m) * 64 +
                                      ((kc * 4 + quad) ^ mx7) * 8);
#pragma unroll
    for (int nt = 0; nt < 4; ++nt)
#pragma unroll
      for (int kc = 0; kc < 2; ++kc)
        bf[nt][kc] = *(const bf16x8*)(Bs + (nh + nt * 16 + m) * 64 +
                                      ((kc * 4 + quad) ^ mx7) * 8);
#pragma unroll
    for (int mt = 0; mt < 4; ++mt)
#pragma unroll
      for (int nt = 0; nt < 4; ++nt)
#pragma unroll
        for (int kc = 0; kc < 2; ++kc)
          acc[mt][nt] = __builtin_amdgcn_mfma_f32_16x16x32_bf16(
              af[mt][kc], bf[nt][kc], acc[mt][nt], 0, 0, 0);
  }
  if (mode == 2) {
    // V^T scatter: value at (token row, channel col) -> Vt[b][h][d][s]
#pragma unroll
    for (int mt = 0; mt < 4; ++mt)
#pragma unroll
      for (int nt = 0; nt < 4; ++nt) {
        int row0 = m0 + mh + mt * 16 + quad * 4;
        int col = n0 + nh + nt * 16 + m;
        int b_ = row0 >> 11, s_ = row0 & (NS - 1);
        int h_ = col >> 6, d_ = col & (DEP - 1);
        uint2 p;
        p.x = pk2(acc[mt][nt][0] * alpha, acc[mt][nt][1] * alpha);
        p.y = pk2(acc[mt][nt][2] * alpha, acc[mt][nt][3] * alpha);
        *(uint2*)(Cout + (size_t)((b_ * NH + h_) * DEP + d_) * NS + s_) = p;
      }
  } else {
#pragma unroll
    for (int mt = 0; mt < 4; ++mt)
#pragma unroll
      for (int nt = 0; nt < 4; ++nt)
#pragma unroll
        for (int r = 0; r < 4; ++r) {
          int row = m0 + mh + mt * 16 + quad * 4 + r;
          int col = n0 + nh + nt * 16 + m;
          Cout[(size_t)row * ND + col] = f2b(acc[mt][nt][r] * alpha);
        }
  }
}

__global__ __launch_bounds__(256) void qkv_gemm(
    const short* __restrict__ xb, const short* __restrict__ yb,
    const short* __restrict__ Wqt, const short* __restrict__ Wkt,
    const short* __restrict__ Wvt, short* __restrict__ Qb,
    short* __restrict__ Kb, short* __restrict__ Vtb) {
  if (blockIdx.z == 0)
    gemm128(xb, Wqt, Qb, 1, QSCALE);  // scale + log2e folded into Q
  else if (blockIdx.z == 1)
    gemm128(yb, Wkt, Kb, 1, 1.0f);
  else
    gemm128(yb, Wvt, Vtb, 2, 1.0f);
}

// ---------------------------------------------------------------------------
// Output GEMM: 128x64 tile, BK=64, double-buffered DMA, swizzled LDS,
// fp32 row-major out.  Grid 512 = 2 blocks/CU.
// ---------------------------------------------------------------------------
__global__ __launch_bounds__(256) void out_gemm(const short* __restrict__ A,
                                                const short* __restrict__ Bt,
                                                float* __restrict__ Cout) {
  __shared__ short As[2][128 * 64];
  __shared__ short Bs[2][64 * 64];
  const int t = threadIdx.x;
  const int wave = t >> 6, lane = t & 63;
  const int m = lane & 15, quad = lane >> 4;
  const int m0 = blockIdx.y * 128, n0 = blockIdx.x * 64;
  const int mh = (wave >> 1) * 64, nh = (wave & 1) * 32;
  const int r8 = lane >> 3;
  const int c8 = (lane & 7) ^ r8;
  const int mx7 = m & 7;
  f32x4 acc[4][2];
#pragma unroll
  for (int i = 0; i < 4; ++i)
#pragma unroll
    for (int j = 0; j < 2; ++j) acc[i][j] = (f32x4){0.f, 0.f, 0.f, 0.f};

#pragma unroll
  for (int i = 0; i < 4; ++i)
    dma16(A + (size_t)(m0 + i * 32 + wave * 8 + r8) * ND + c8 * 8,
          As[0] + (i * 256 + wave * 64) * 8);
#pragma unroll
  for (int i = 0; i < 2; ++i)
    dma16(Bt + (size_t)(n0 + i * 32 + wave * 8 + r8) * ND + c8 * 8,
          Bs[0] + (i * 256 + wave * 64) * 8);

  int buf = 0;
  for (int k0 = 0; k0 < ND; k0 += 64, buf ^= 1) {
    __syncthreads();
    if (k0 + 64 < ND) {
#pragma unroll
      for (int i = 0; i < 4; ++i)
        dma16(A + (size_t)(m0 + i * 32 + wave * 8 + r8) * ND + k0 + 64 + c8 * 8,
              As[buf ^ 1] + (i * 256 + wave * 64) * 8);
#pragma unroll
      for (int i = 0; i < 2; ++i)
        dma16(Bt + (size_t)(n0 + i * 32 + wave * 8 + r8) * ND + k0 + 64 +
                  c8 * 8,
              Bs[buf ^ 1] + (i * 256 + wave * 64) * 8);
    }
    bf16x8 af[4][2], bf[2][2];
#pragma unroll
    for (int mt = 0; mt < 4; ++mt)
#pragma unroll
      for (int kc = 0; kc < 2; ++kc)
        af[mt][kc] = *(const bf16x8*)(As[buf] + (mh + mt * 16 + m) * 64 +
                                      ((kc * 4 + quad) ^ mx7) * 8);
#pragma unroll
    for (int nt = 0; nt < 2; ++nt)
#pragma unroll
      for (int kc = 0; kc < 2; ++kc)
        bf[nt][kc] = *(const bf16x8*)(Bs[buf] + (nh + nt * 16 + m) * 64 +
                                      ((kc * 4 + quad) ^ mx7) * 8);
#pragma unroll
    for (int mt = 0; mt < 4; ++mt)
#pragma unroll
      for (int nt = 0; nt < 2; ++nt)
#pragma unroll
        for (int kc = 0; kc < 2; ++kc)
          acc[mt][nt] = __builtin_amdgcn_mfma_f32_16x16x32_bf16(
              af[mt][kc], bf[nt][kc], acc[mt][nt], 0, 0, 0);
  }
#pragma unroll
  for (int mt = 0; mt < 4; ++mt)
#pragma unroll
    for (int nt = 0; nt < 2; ++nt)
#pragma unroll
      for (int r = 0; r < 4; ++r) {
        int row = m0 + mh + mt * 16 + quad * 4 + r;
        int col = n0 + nh + nt * 16 + m;
        Cout[(size_t)row * ND + col] = acc[mt][nt][r];
      }
}

// ---------------------------------------------------------------------------
// Flash attention, S^T formulation, max-free softmax (raw v_exp_f32).
// Block = 64 q x (b,h), 4 waves x 16 q, grid 1024, double-buffered K/V DMA.
// ---------------------------------------------------------------------------
__global__ __launch_bounds__(256) void attn_mfma(const short* __restrict__ Qb,
                                                 const short* __restrict__ Kb,
                                                 const short* __restrict__ Vtb,
                                                 short* __restrict__ Ob) {
  __shared__ short Ks[2][64 * 64];   // [kv][d], swizzled
  __shared__ short Vts[2][64 * 64];  // [d][kv], swizzled
  __shared__ short Pt[64 * 64];      // [q][kv], swizzled, wave-private bands
  const int t = threadIdx.x;
  const int wave = t >> 6, lane = t & 63;
  const int m = lane & 15, quad = lane >> 4;
  const int bh = blockIdx.y, b = bh >> 3, h = bh & 7;
  const int q0 = blockIdx.x * 64;
  const int wq = wave * 16;
  const size_t rowb = (size_t)b * NS;
  const short* Vtbase = Vtb + (size_t)(bh * DEP) * NS;
  const int r8 = lane >> 3;
  const int c8 = (lane & 7) ^ r8;
  const int mx7 = m & 7;

  bf16x8 qf[2];
#pragma unroll
  for (int kc = 0; kc < 2; ++kc)
    qf[kc] = *(const bf16x8*)(Qb + (rowb + q0 + wq + m) * ND + h * DEP +
                              kc * 32 + quad * 8);

  float l_ = 0.0f;
  f32x4 Ot[4];
#pragma unroll
  for (int mt = 0; mt < 4; ++mt) Ot[mt] = (f32x4){0.f, 0.f, 0.f, 0.f};

#pragma unroll
  for (int i = 0; i < 2; ++i) {
    int row = i * 32 + wave * 8 + r8;
    dma16(Kb + (rowb + row) * ND + h * DEP + c8 * 8,
          Ks[0] + (i * 256 + wave * 64) * 8);
    dma16(Vtbase + (size_t)row * NS + c8 * 8,
          Vts[0] + (i * 256 + wave * 64) * 8);
  }

  int buf = 0;
  for (int kv0 = 0; kv0 < NS; kv0 += 64, buf ^= 1) {
    __syncthreads();
    if (kv0 + 64 < NS) {
#pragma unroll
      for (int i = 0; i < 2; ++i) {
        int row = i * 32 + wave * 8 + r8;
        dma16(Kb + (rowb + kv0 + 64 + row) * ND + h * DEP + c8 * 8,
              Ks[buf ^ 1] + (i * 256 + wave * 64) * 8);
        dma16(Vtbase + (size_t)row * NS + kv0 + 64 + c8 * 8,
              Vts[buf ^ 1] + (i * 256 + wave * 64) * 8);
      }
    }

    f32x4 St[4];
#pragma unroll
    for (int mt = 0; mt < 4; ++mt) St[mt] = (f32x4){0.f, 0.f, 0.f, 0.f};
#pragma unroll
    for (int mt = 0; mt < 4; ++mt)
#pragma unroll
      for (int kc = 0; kc < 2; ++kc) {
        bf16x8 kf = *(const bf16x8*)(Ks[buf] + (mt * 16 + m) * 64 +
                                     ((kc * 4 + quad) ^ mx7) * 8);
        St[mt] = __builtin_amdgcn_mfma_f32_16x16x32_bf16(kf, qf[kc], St[mt],
                                                         0, 0, 0);
      }

    float rs = 0.0f;
#pragma unroll
    for (int mt = 0; mt < 4; ++mt) {
      float p0 = __builtin_amdgcn_exp2f(St[mt][0]);
      float p1 = __builtin_amdgcn_exp2f(St[mt][1]);
      float p2 = __builtin_amdgcn_exp2f(St[mt][2]);
      float p3 = __builtin_amdgcn_exp2f(St[mt][3]);
      rs += (p0 + p1) + (p2 + p3);
      uint2 pk;
      pk.x = pk2(p0, p1);
      pk.y = pk2(p2, p3);
      *(uint2*)(Pt + (wq + m) * 64 + ((mt * 2 + (quad >> 1)) ^ mx7) * 8 +
                (quad & 1) * 4) = pk;
    }
    l_ += rs;

#pragma unroll
    for (int kc = 0; kc < 2; ++kc) {
      bf16x8 pf = *(const bf16x8*)(Pt + (wq + m) * 64 +
                                   ((kc * 4 + quad) ^ mx7) * 8);
#pragma unroll
      for (int mt = 0; mt < 4; ++mt) {
        bf16x8 vf = *(const bf16x8*)(Vts[buf] + (mt * 16 + m) * 64 +
                                     ((kc * 4 + quad) ^ mx7) * 8);
        Ot[mt] = __builtin_amdgcn_mfma_f32_16x16x32_bf16(vf, pf, Ot[mt],
                                                         0, 0, 0);
      }
    }
  }

  l_ += __shfl_xor(l_, 16, 64);
  l_ += __shfl_xor(l_, 32, 64);
  float linv = 1.0f / l_;
  size_t row = rowb + q0 + wq + m;
#pragma unroll
  for (int mt = 0; mt < 4; ++mt)
#pragma unroll
    for (int r = 0; r < 4; ++r)
      Ob[row * ND + h * DEP + mt * 16 + quad * 4 + r] = f2b(Ot[mt][r] * linv);
}

// ---------------------------------------------------------------------------
extern "C" void kernel_launch(void* const* d_in, const int* in_sizes, int n_in,
                              void* d_out, int out_size, void* d_ws,
                              size_t ws_size, hipStream_t stream) {
  const float* x = (const float*)d_in[0];
  const float* y = (const float*)d_in[1];
  const float* Wq = (const float*)d_in[2];
  const float* Wk = (const float*)d_in[3];
  const float* Wv = (const float*)d_in[4];
  const float* Wo = (const float*)d_in[5];
  float* out = (float*)d_out;

  const size_t mat = (size_t)NB * NS * ND;
  const size_t wsz = (size_t)ND * ND;
  short* xb = (short*)d_ws;
  short* yb = xb + mat;
  short* Wqt = yb + mat;
  short* Wkt = Wqt + wsz;
  short* Wvt = Wkt + wsz;
  short* Wot = Wvt + wsz;
  short* Qb = Wot + wsz;
  short* Kb = Qb + mat;
  short* Vtb = Kb + mat;
  short* attnb = xb;  // reuse: xb dead after QKV GEMM

  prep<<<dim3(mat / 1024, 3), 256, 0, stream>>>(x, y, Wq, Wk, Wv, Wo, xb, yb,
                                                Wqt, Wkt, Wvt, Wot);
  qkv_gemm<<<dim3(ND / 128, (NB * NS) / 128, 3), 256, 0, stream>>>(
      xb, yb, Wqt, Wkt, Wvt, Qb, Kb, Vtb);
  attn_mfma<<<dim3(NS / 64, NB * NH), 256, 0, stream>>>(Qb, Kb, Vtb, attnb);
  out_gemm<<<dim3(ND / 64, (NB * NS) / 128), 256, 0, stream>>>(attnb, Wot,
                                                               out);
}